// Round 1
// baseline (223.856 us; speedup 1.0000x reference)
//
#include <hip/hip_runtime.h>
#include <math.h>

#define MTOT 9216
#define A_ 36
#define D0_ 64
#define EDGE_ 32
#define RBF_ 16
#define KNN 24
#define QIN_ 67    // D0 + KC
#define EPS_ 1e-5f

// ---- prep: state passthrough copy + pact build + xyz passthrough (fused) ----
__global__ void k_prep(const int* __restrict__ seq, const float* __restrict__ xyz,
                       const int* __restrict__ aamask,
                       const float4* __restrict__ state4, float4* __restrict__ out_state4,
                       float4* __restrict__ pact, float* __restrict__ out_xyz,
                       int* __restrict__ cnt) {
    int t = blockIdx.x * blockDim.x + threadIdx.x;
    if (t < MTOT * D0_ / 4) out_state4[t] = state4[t];
    if (t < MTOT) {
        int r = t / A_;
        int a = t - r * A_;
        int mk = (aamask[seq[r] * A_ + a] != 0);
        float x0 = xyz[t * 3 + 0], x1 = xyz[t * 3 + 1], x2 = xyz[t * 3 + 2];
        out_xyz[t * 3 + 0] = x0;
        out_xyz[t * 3 + 1] = x1;
        out_xyz[t * 3 + 2] = x2;
        if (mk) {
            int p = atomicAdd(cnt, 1);   // compiler wave-aggregates
            pact[p] = make_float4(x0, x1, x2, __int_as_float(t));
        }
    }
}

// ------- exact top-24, wave-per-atom, lane-parallel histogram (VALU-only),
// ------- ballot-compacted pass B, 4-deep load pipeline ---------------------
#define CAPN 256
#define WPB 2
#define UNR 4

__global__ __launch_bounds__(128) void k_nbr(const float4* __restrict__ pact,
                                             const int* __restrict__ cnt,
                                             int* __restrict__ idx) {
    __shared__ uint2 s_cand[WPB][CAPN];   // per-wave slice, 4 KB total

    const int nact = *cnt;
    const int lane = threadIdx.x & 63;
    const int wv = threadIdx.x >> 6;
    const int slot = blockIdx.x * WPB + wv;
    if (slot >= nact) return;            // wave-uniform exit; no block barriers

    const float4 pq = pact[slot];
    const int ia = __float_as_int(pq.w);
    const unsigned long long lmask = (1ULL << lane) - 1ULL;

    // ---- pass A: cumulative histogram, 16 raw-bits thresholds ----
    // Lane-parallel: each lane keeps its own 16 counters in VGPRs (v_cmp+addc
    // chains, 16-way ILP, zero SALU) instead of 64 ballot->s_bcnt1 round-trips
    // per chunk that oversubscribed the CU's single scalar unit (VALUBusy 26%).
    unsigned cum[16];
    #pragma unroll
    for (int b = 0; b < 16; ++b) cum[b] = 0u;

    for (int base = 0; base < nact; base += 64 * UNR) {
        float4 p[UNR];
        #pragma unroll
        for (int u = 0; u < UNR; ++u) p[u] = pact[base + u * 64 + lane];  // padded: OOB-safe
        #pragma unroll
        for (int u = 0; u < UNR; ++u) {
            int c = base + u * 64 + lane;
            int j = __float_as_int(p[u].w);
            float dx = p[u].x - pq.x, dy = p[u].y - pq.y, dz = p[u].z - pq.z;
            float d2 = dx * dx + dy * dy + dz * dz;
            unsigned bt = (c < nact && j != ia) ? __float_as_uint(d2) : 0xFFFFFFFFu;
            #pragma unroll
            for (int b = 0; b < 16; ++b) {
                const unsigned L = (unsigned)(242 + 2 * b) << 22;   // == bin <= 2b+1
                cum[b] += (bt < L) ? 1u : 0u;
            }
        }
    }
    // wave-wide butterfly reduce; every lane ends with the full-wave totals
    #pragma unroll
    for (int b = 0; b < 16; ++b) {
        unsigned v = cum[b];
        #pragma unroll
        for (int off = 32; off > 0; off >>= 1)
            v += (unsigned)__shfl_xor((int)v, off, 64);
        cum[b] = v;
    }

    // ---- threshold of the 24th smallest (uniform across lanes) ----
    int bsel = 15;
    #pragma unroll
    for (int b = 15; b >= 0; --b) if (cum[b] >= KNN) bsel = b;
    const unsigned limit = (unsigned)(242 + 2 * bsel) << 22;

    // ---- pass B: ballot-compacted candidate collection (superset of top-24) ----
    int nsel = 0;
    for (int base = 0; base < nact; base += 64 * UNR) {
        float4 p[UNR];
        #pragma unroll
        for (int u = 0; u < UNR; ++u) p[u] = pact[base + u * 64 + lane];
        #pragma unroll
        for (int u = 0; u < UNR; ++u) {
            int c = base + u * 64 + lane;
            int j = __float_as_int(p[u].w);
            float dx = p[u].x - pq.x, dy = p[u].y - pq.y, dz = p[u].z - pq.z;
            float d2 = dx * dx + dy * dy + dz * dz;
            unsigned bits = (c < nact && j != ia) ? __float_as_uint(d2) : 0xFFFFFFFFu;
            bool sel = bits < limit;
            unsigned long long m = __ballot(sel);
            int pos = nsel + (int)__popcll(m & lmask);
            if (sel && pos < CAPN) s_cand[wv][pos] = make_uint2(bits, (unsigned)j);
            nsel += (int)__popcll(m);
        }
    }
    __builtin_amdgcn_wave_barrier();

    // ---- exact rank select ((d2, j) lex == lax.top_k tie-break) ----
    int n = min(nsel, CAPN);
    for (int c = lane; c < n; c += 64) {
        uint2 my = s_cand[wv][c];
        int rank = 0;
        for (int c2 = 0; c2 < n; ++c2) {
            uint2 o = s_cand[wv][c2];
            rank += (o.x < my.x) || (o.x == my.x && o.y < my.y);
        }
        if (rank < KNN) idx[ia * KNN + rank] = (int)my.y;
    }
}

// ---------------- per-atom attention, rank-reduced (R3 kernel, verbatim) -------
__global__ __launch_bounds__(64, 2) void k_attn(
    const float* __restrict__ xyz, const int* __restrict__ seq,
    const int* __restrict__ num_bonds, const float* __restrict__ state,
    const float* __restrict__ grads,
    const float* __restrict__ We, const float* __restrict__ be,
    const float* __restrict__ Wq, const float* __restrict__ Wk,
    const float* __restrict__ Wv0, const float* __restrict__ Wv1,
    const float* __restrict__ Wo0, const float* __restrict__ Wself,
    const float* __restrict__ b0,
    const float4* __restrict__ pact, const int* __restrict__ cnt,
    const int* __restrict__ idxbuf,
    float* __restrict__ out_xyz, float* __restrict__ out_state) {
    const int nact = *cnt;
    if ((int)blockIdx.x >= nact) return;
    const int i = __float_as_int(pact[blockIdx.x].w);
    const int lane = threadIdx.x;
    const int l15 = lane & 15;
    const int h = lane >> 4;

    __shared__ float s_kin[KNN][100];   // [node0(64) | e(32) | inv(3) | pad]
    __shared__ float s_qw[4][100];      // Wk folded with q, per head
    __shared__ float s_wkin[4][100];    // attn-weighted kin, per head
    __shared__ float s_dir[KNN][4];
    __shared__ float s_rbf[KNN][RBF_];
    __shared__ float s_l1j[KNN][3][3];
    __shared__ float s_qin[68];
    __shared__ float s_q[64];
    __shared__ float s_logit[4][KNN];
    __shared__ float s_attn[4][KNN];
    __shared__ float s_o0[64];
    __shared__ float s_v1[KNN][16];
    __shared__ float s_coef[KNN][4];
    __shared__ int   s_j[KNN];
    __shared__ int   s_ok[KNN];
    __shared__ int   s_bc[KNN];
    __shared__ float s_xi[3];

    // ---- stage per-atom inputs ----
    s_qin[lane] = state[i * D0_ + lane];
    if (lane < 3) {
        float g0 = grads[(lane * MTOT + i) * 3 + 0];
        float g1 = grads[(lane * MTOT + i) * 3 + 1];
        float g2 = grads[(lane * MTOT + i) * 3 + 2];
        s_qin[D0_ + lane] = sqrtf(g0 * g0 + g1 * g1 + g2 * g2 + EPS_);
        s_xi[lane] = xyz[i * 3 + lane];
    }
    if (lane < KNN) {
        int j = idxbuf[i * KNN + lane];
        int ok = (j >= 0 && j < MTOT);
        int jj = ok ? j : 0;
        s_j[lane] = jj;
        s_ok[lane] = ok;
        float dx = xyz[jj * 3 + 0] - xyz[i * 3 + 0];
        float dy = xyz[jj * 3 + 1] - xyz[i * 3 + 1];
        float dz = xyz[jj * 3 + 2] - xyz[i * 3 + 2];
        float dist = sqrtf(dx * dx + dy * dy + dz * dz + EPS_);
        s_dir[lane][0] = dx / dist;
        s_dir[lane][1] = dy / dist;
        s_dir[lane][2] = dz / dist;
        s_dir[lane][3] = dist;
        int ri = i / A_, ai = i - ri * A_;
        int rj = jj / A_, aj = jj - rj * A_;
        int b = 0;
        if (rj == ri) b = num_bonds[(seq[ri] * A_ + ai) * A_ + aj];
        s_bc[lane] = min(max(b, 0), 4);
    }
    __syncthreads();

    // ---- q projection ----
    {
        float q = 0.0f;
        for (int c = 0; c < QIN_; ++c) q += s_qin[c] * Wq[c * 64 + lane];
        s_q[lane] = q;
    }
    // ---- rbf ----
    for (int f = lane; f < KNN * RBF_; f += 64) {
        int k = f >> 4, r = f & 15;
        float mu = (6.0f / 15.0f) * (float)r;
        float d = s_dir[k][3] - mu;
        s_rbf[k][r] = expf(-d * d * 2.0f);
    }
    // ---- neighbor node0 gather ----
    for (int k = 0; k < KNN; ++k) s_kin[k][lane] = state[s_j[k] * D0_ + lane];
    // ---- l1 invariants + stash l1j ----
    for (int f = lane; f < KNN * 3; f += 64) {
        int k = f / 3, c = f - 3 * k;
        int jj = s_j[k];
        float g0 = grads[(c * MTOT + jj) * 3 + 0];
        float g1 = grads[(c * MTOT + jj) * 3 + 1];
        float g2 = grads[(c * MTOT + jj) * 3 + 2];
        s_l1j[k][c][0] = g0; s_l1j[k][c][1] = g1; s_l1j[k][c][2] = g2;
        s_kin[k][96 + c] = g0 * s_dir[k][0] + g1 * s_dir[k][1] + g2 * s_dir[k][2];
    }
    if (lane < KNN) s_kin[lane][99] = 0.0f;
    __syncthreads();

    // ---- edge embedding -> kin[:, 64:96] ----
    for (int f = lane; f < KNN * EDGE_; f += 64) {
        int k = f >> 5, d = f & 31;
        float acc = be[d] + We[(RBF_ + s_bc[k]) * EDGE_ + d];
        #pragma unroll
        for (int r = 0; r < RBF_; ++r) acc += s_rbf[k][r] * We[r * EDGE_ + d];
        s_kin[k][64 + d] = acc;
    }
    // ---- fold q into Wk: qW[h][c] = sum_d q[h,d] * Wk[c, h*16+d] ----
    for (int t = 0; t < 7; ++t) {
        int c = t * 16 + l15;
        if (c < 99) {
            const float* wk = &Wk[c * 64 + h * 16];
            float acc = 0.0f;
            #pragma unroll
            for (int d = 0; d < 16; ++d) acc += s_q[h * 16 + d] * wk[d];
            s_qw[h][c] = acc;
        }
    }
    __syncthreads();

    // ---- logits[h][k] = kin[k] . qW[h] ----
    for (int f = lane; f < 96; f += 64) {
        int k = f >> 2, hh = f & 3;
        const float4* k4 = (const float4*)s_kin[k];
        const float4* q4 = (const float4*)s_qw[hh];
        float acc = 0.0f;
        #pragma unroll
        for (int c4 = 0; c4 < 24; ++c4) {
            float4 a = k4[c4], b = q4[c4];
            acc += a.x * b.x + a.y * b.y + a.z * b.z + a.w * b.w;
        }
        acc += s_kin[k][96] * s_qw[hh][96] + s_kin[k][97] * s_qw[hh][97]
             + s_kin[k][98] * s_qw[hh][98];
        s_logit[hh][k] = s_ok[k] ? acc * 0.25f : -1e9f;
    }
    __syncthreads();

    // ---- softmax ----
    float attn[KNN];
    {
        float mx = -1e30f;
        #pragma unroll
        for (int k = 0; k < KNN; ++k) { attn[k] = s_logit[h][k]; mx = fmaxf(mx, attn[k]); }
        float ss = 0.0f;
        #pragma unroll
        for (int k = 0; k < KNN; ++k) { attn[k] = expf(attn[k] - mx); ss += attn[k]; }
        float rs = 1.0f / ss;
        #pragma unroll
        for (int k = 0; k < KNN; ++k) attn[k] *= rs;
    }
    s_attn[h][l15] = attn[l15];
    if (l15 < 8) s_attn[h][16 + l15] = attn[16 + l15];

    // ---- wkin[h][c] = sum_k attn[k] * kin[k][c] ----
    for (int t = 0; t < 7; ++t) {
        int c = t * 16 + l15;
        if (c < 99) {
            float acc = 0.0f;
            #pragma unroll
            for (int k = 0; k < KNN; ++k) acc += attn[k] * s_kin[k][c];
            s_wkin[h][c] = acc;
        }
    }
    // ---- v1[k][u] = kin[k] . Wv1[:,u] ----
    for (int t = 0; t < 6; ++t) {
        int k = (t * 64 + lane) >> 4;
        const float4* k4 = (const float4*)s_kin[k];
        const float* wv = &Wv1[l15];
        float acc = 0.0f;
        #pragma unroll
        for (int c4 = 0; c4 < 24; ++c4) {
            float4 a = k4[c4];
            acc += a.x * wv[(c4 * 4 + 0) * 16] + a.y * wv[(c4 * 4 + 1) * 16]
                 + a.z * wv[(c4 * 4 + 2) * 16] + a.w * wv[(c4 * 4 + 3) * 16];
        }
        acc += s_kin[k][96] * wv[96 * 16] + s_kin[k][97] * wv[97 * 16]
             + s_kin[k][98] * wv[98 * 16];
        s_v1[k][l15] = acc;
    }
    __syncthreads();

    // ---- o0[lane] = sum_c wkin[h][c] * Wv0[c, lane] ----
    {
        float o0 = 0.0f;
        for (int c = 0; c < 99; ++c) o0 += s_wkin[h][c] * Wv0[c * 64 + lane];
        s_o0[lane] = o0;
    }
    __syncthreads();

    // ---- out0 = o0 @ Wo0 + node0 @ Wself + b0 ----
    {
        float acc = b0[lane];
        for (int t = 0; t < 64; ++t) acc += s_o0[t] * Wo0[t * 64 + lane];
        for (int t = 0; t < 64; ++t) acc += s_qin[t] * Wself[t * 64 + lane];
        out_state[i * D0_ + lane] = acc;
    }
    // ---- coef[k][c] = sum_h attn[h][k] * v1[k][h*4+c] ----
    for (int f = lane; f < KNN * 4; f += 64) {
        int k = f >> 2, c = f & 3;
        float a2 = 0.0f;
        #pragma unroll
        for (int hh = 0; hh < 4; ++hh) a2 += s_attn[hh][k] * s_v1[k][hh * 4 + c];
        s_coef[k][c] = a2;
    }
    __syncthreads();

    // ---- vector message -> xyz shift ----
    if (lane < 3) {
        float o1 = 0.0f;
        #pragma unroll
        for (int k = 0; k < KNN; ++k) {
            float t = s_coef[k][0] * s_dir[k][lane];
            t += s_coef[k][1] * s_l1j[k][0][lane];
            t += s_coef[k][2] * s_l1j[k][1][lane];
            t += s_coef[k][3] * s_l1j[k][2][lane];
            o1 += t;
        }
        out_xyz[i * 3 + lane] = s_xi[lane] + o1 / 100.0f;
    }
}

extern "C" void kernel_launch(void* const* d_in, const int* in_sizes, int n_in,
                              void* d_out, int out_size, void* d_ws, size_t ws_size,
                              hipStream_t stream) {
    const int*   seq    = (const int*)d_in[0];
    const float* xyz    = (const float*)d_in[1];
    const int*   aamask = (const int*)d_in[2];
    const int*   nbonds = (const int*)d_in[3];
    const float* state  = (const float*)d_in[4];
    const float* grads  = (const float*)d_in[5];
    const float* We    = (const float*)d_in[7];
    const float* be    = (const float*)d_in[8];
    const float* Wq    = (const float*)d_in[9];
    const float* Wk    = (const float*)d_in[10];
    const float* Wv0   = (const float*)d_in[11];
    const float* Wv1   = (const float*)d_in[12];
    const float* Wo0   = (const float*)d_in[13];
    const float* Wself = (const float*)d_in[14];
    const float* b0    = (const float*)d_in[15];

    float* out_xyz   = (float*)d_out;
    float* out_state = out_xyz + MTOT * 3;

    char* ws = (char*)d_ws;
    int*    cnt  = (int*)ws;                              // 16 B
    float4* pact = (float4*)(ws + 16);                    // (MTOT+256)*16 = 151552 B
    int*    idx  = (int*)(ws + 16 + 151552);              // 884736 B

    hipMemsetAsync(cnt, 0, 16, stream);
    k_prep<<<(MTOT * D0_ / 4 + 255) / 256, 256, 0, stream>>>(
        seq, xyz, aamask, (const float4*)state, (float4*)out_state,
        pact, out_xyz, cnt);
    k_nbr<<<(MTOT + WPB - 1) / WPB, WPB * 64, 0, stream>>>(pact, cnt, idx);
    k_attn<<<MTOT, 64, 0, stream>>>(xyz, seq, nbonds, state, grads, We, be, Wq, Wk,
                                    Wv0, Wv1, Wo0, Wself, b0, pact, cnt, idx,
                                    out_xyz, out_state);
}

// Round 2
// 211.740 us; speedup vs baseline: 1.0572x; 1.0572x over previous
//
#include <hip/hip_runtime.h>
#include <math.h>

#define MTOT 9216
#define A_ 36
#define D0_ 64
#define EDGE_ 32
#define RBF_ 16
#define KNN 24
#define QIN_ 67    // D0 + KC
#define EPS_ 1e-5f

// ---- prep: state passthrough copy + pact build + xyz passthrough (fused) ----
__global__ void k_prep(const int* __restrict__ seq, const float* __restrict__ xyz,
                       const int* __restrict__ aamask,
                       const float4* __restrict__ state4, float4* __restrict__ out_state4,
                       float4* __restrict__ pact, float* __restrict__ out_xyz,
                       int* __restrict__ cnt) {
    int t = blockIdx.x * blockDim.x + threadIdx.x;
    if (t < MTOT * D0_ / 4) out_state4[t] = state4[t];
    if (t < MTOT) {
        int r = t / A_;
        int a = t - r * A_;
        int mk = (aamask[seq[r] * A_ + a] != 0);
        float x0 = xyz[t * 3 + 0], x1 = xyz[t * 3 + 1], x2 = xyz[t * 3 + 2];
        out_xyz[t * 3 + 0] = x0;
        out_xyz[t * 3 + 1] = x1;
        out_xyz[t * 3 + 2] = x2;
        if (mk) {
            int p = atomicAdd(cnt, 1);   // compiler wave-aggregates
            pact[p] = make_float4(x0, x1, x2, __int_as_float(t));
        }
    }
}

// ------- exact top-24, wave-per-atom, lane-parallel histogram (VALU-only),
// ------- register ping-pong prefetch to hide L2 latency --------------------
#define CAPN 256
#define WPB 2
#define UNR 4
#define CHUNK (64 * UNR)

__global__ __launch_bounds__(128) void k_nbr(const float4* __restrict__ pact,
                                             const int* __restrict__ cnt,
                                             int* __restrict__ idx) {
    __shared__ uint2 s_cand[WPB][CAPN];   // per-wave slice, 4 KB total

    const int nact = *cnt;
    const int lane = threadIdx.x & 63;
    const int wv = threadIdx.x >> 6;
    const int slot = blockIdx.x * WPB + wv;
    if (slot >= nact) return;            // wave-uniform exit; no block barriers

    const float4 pq = pact[slot];
    const int ia = __float_as_int(pq.w);
    const unsigned long long lmask = (1ULL << lane) - 1ULL;

    // prefetch helper: wave-uniform clamped base (chunk-0 dummy when OOB;
    // pact padded by 256 entries so all lanes stay in-bounds)
    auto pre = [&](float4* p, int base) {
        int b2 = (base < nact) ? base : 0;
        #pragma unroll
        for (int u = 0; u < UNR; ++u) p[u] = pact[b2 + u * 64 + lane];
    };

    // ---- pass A: cumulative histogram, 16 raw-bits thresholds ----
    // Lane-parallel VGPR counters (16-way ILP, no SALU), ping-pong prefetch:
    // chunk n+1's loads are in flight while chunk n computes (~340 cyc compute
    // > ~250 cyc L2 latency), so the VALU never waits on vmcnt in steady state.
    unsigned cum[16];
    #pragma unroll
    for (int b = 0; b < 16; ++b) cum[b] = 0u;

    auto histo = [&](const float4* p, int base) {
        #pragma unroll
        for (int u = 0; u < UNR; ++u) {
            int c = base + u * 64 + lane;
            int j = __float_as_int(p[u].w);
            float dx = p[u].x - pq.x, dy = p[u].y - pq.y, dz = p[u].z - pq.z;
            float d2 = dx * dx + dy * dy + dz * dz;
            unsigned bt = (c < nact && j != ia) ? __float_as_uint(d2) : 0xFFFFFFFFu;
            #pragma unroll
            for (int b = 0; b < 16; ++b) {
                const unsigned L = (unsigned)(242 + 2 * b) << 22;   // == bin <= 2b+1
                cum[b] += (bt < L) ? 1u : 0u;
            }
        }
    };

    float4 pA[UNR], pB[UNR];
    pre(pA, 0);
    for (int base = 0; base < nact; base += 2 * CHUNK) {
        pre(pB, base + CHUNK);
        histo(pA, base);
        pre(pA, base + 2 * CHUNK);
        if (base + CHUNK < nact) histo(pB, base + CHUNK);
    }

    // wave-wide butterfly reduce; every lane ends with the full-wave totals
    #pragma unroll
    for (int b = 0; b < 16; ++b) {
        unsigned v = cum[b];
        #pragma unroll
        for (int off = 32; off > 0; off >>= 1)
            v += (unsigned)__shfl_xor((int)v, off, 64);
        cum[b] = v;
    }

    // ---- threshold of the 24th smallest (uniform across lanes) ----
    int bsel = 15;
    #pragma unroll
    for (int b = 15; b >= 0; --b) if (cum[b] >= KNN) bsel = b;
    const unsigned limit = (unsigned)(242 + 2 * bsel) << 22;

    // ---- pass B: ballot-compacted candidate collection (superset of top-24) ----
    int nsel = 0;
    auto collect = [&](const float4* p, int base) {
        #pragma unroll
        for (int u = 0; u < UNR; ++u) {
            int c = base + u * 64 + lane;
            int j = __float_as_int(p[u].w);
            float dx = p[u].x - pq.x, dy = p[u].y - pq.y, dz = p[u].z - pq.z;
            float d2 = dx * dx + dy * dy + dz * dz;
            unsigned bits = (c < nact && j != ia) ? __float_as_uint(d2) : 0xFFFFFFFFu;
            bool sel = bits < limit;
            unsigned long long m = __ballot(sel);
            int pos = nsel + (int)__popcll(m & lmask);
            if (sel && pos < CAPN) s_cand[wv][pos] = make_uint2(bits, (unsigned)j);
            nsel += (int)__popcll(m);
        }
    };

    pre(pA, 0);
    for (int base = 0; base < nact; base += 2 * CHUNK) {
        pre(pB, base + CHUNK);
        collect(pA, base);
        pre(pA, base + 2 * CHUNK);
        if (base + CHUNK < nact) collect(pB, base + CHUNK);
    }
    __builtin_amdgcn_wave_barrier();

    // ---- exact rank select ((d2, j) lex == lax.top_k tie-break) ----
    int n = min(nsel, CAPN);
    for (int c = lane; c < n; c += 64) {
        uint2 my = s_cand[wv][c];
        int rank = 0;
        for (int c2 = 0; c2 < n; ++c2) {
            uint2 o = s_cand[wv][c2];
            rank += (o.x < my.x) || (o.x == my.x && o.y < my.y);
        }
        if (rank < KNN) idx[ia * KNN + rank] = (int)my.y;
    }
}

// ---------------- per-atom attention, rank-reduced (R3 kernel, verbatim) -------
__global__ __launch_bounds__(64, 2) void k_attn(
    const float* __restrict__ xyz, const int* __restrict__ seq,
    const int* __restrict__ num_bonds, const float* __restrict__ state,
    const float* __restrict__ grads,
    const float* __restrict__ We, const float* __restrict__ be,
    const float* __restrict__ Wq, const float* __restrict__ Wk,
    const float* __restrict__ Wv0, const float* __restrict__ Wv1,
    const float* __restrict__ Wo0, const float* __restrict__ Wself,
    const float* __restrict__ b0,
    const float4* __restrict__ pact, const int* __restrict__ cnt,
    const int* __restrict__ idxbuf,
    float* __restrict__ out_xyz, float* __restrict__ out_state) {
    const int nact = *cnt;
    if ((int)blockIdx.x >= nact) return;
    const int i = __float_as_int(pact[blockIdx.x].w);
    const int lane = threadIdx.x;
    const int l15 = lane & 15;
    const int h = lane >> 4;

    __shared__ float s_kin[KNN][100];   // [node0(64) | e(32) | inv(3) | pad]
    __shared__ float s_qw[4][100];      // Wk folded with q, per head
    __shared__ float s_wkin[4][100];    // attn-weighted kin, per head
    __shared__ float s_dir[KNN][4];
    __shared__ float s_rbf[KNN][RBF_];
    __shared__ float s_l1j[KNN][3][3];
    __shared__ float s_qin[68];
    __shared__ float s_q[64];
    __shared__ float s_logit[4][KNN];
    __shared__ float s_attn[4][KNN];
    __shared__ float s_o0[64];
    __shared__ float s_v1[KNN][16];
    __shared__ float s_coef[KNN][4];
    __shared__ int   s_j[KNN];
    __shared__ int   s_ok[KNN];
    __shared__ int   s_bc[KNN];
    __shared__ float s_xi[3];

    // ---- stage per-atom inputs ----
    s_qin[lane] = state[i * D0_ + lane];
    if (lane < 3) {
        float g0 = grads[(lane * MTOT + i) * 3 + 0];
        float g1 = grads[(lane * MTOT + i) * 3 + 1];
        float g2 = grads[(lane * MTOT + i) * 3 + 2];
        s_qin[D0_ + lane] = sqrtf(g0 * g0 + g1 * g1 + g2 * g2 + EPS_);
        s_xi[lane] = xyz[i * 3 + lane];
    }
    if (lane < KNN) {
        int j = idxbuf[i * KNN + lane];
        int ok = (j >= 0 && j < MTOT);
        int jj = ok ? j : 0;
        s_j[lane] = jj;
        s_ok[lane] = ok;
        float dx = xyz[jj * 3 + 0] - xyz[i * 3 + 0];
        float dy = xyz[jj * 3 + 1] - xyz[i * 3 + 1];
        float dz = xyz[jj * 3 + 2] - xyz[i * 3 + 2];
        float dist = sqrtf(dx * dx + dy * dy + dz * dz + EPS_);
        s_dir[lane][0] = dx / dist;
        s_dir[lane][1] = dy / dist;
        s_dir[lane][2] = dz / dist;
        s_dir[lane][3] = dist;
        int ri = i / A_, ai = i - ri * A_;
        int rj = jj / A_, aj = jj - rj * A_;
        int b = 0;
        if (rj == ri) b = num_bonds[(seq[ri] * A_ + ai) * A_ + aj];
        s_bc[lane] = min(max(b, 0), 4);
    }
    __syncthreads();

    // ---- q projection ----
    {
        float q = 0.0f;
        for (int c = 0; c < QIN_; ++c) q += s_qin[c] * Wq[c * 64 + lane];
        s_q[lane] = q;
    }
    // ---- rbf ----
    for (int f = lane; f < KNN * RBF_; f += 64) {
        int k = f >> 4, r = f & 15;
        float mu = (6.0f / 15.0f) * (float)r;
        float d = s_dir[k][3] - mu;
        s_rbf[k][r] = expf(-d * d * 2.0f);
    }
    // ---- neighbor node0 gather ----
    for (int k = 0; k < KNN; ++k) s_kin[k][lane] = state[s_j[k] * D0_ + lane];
    // ---- l1 invariants + stash l1j ----
    for (int f = lane; f < KNN * 3; f += 64) {
        int k = f / 3, c = f - 3 * k;
        int jj = s_j[k];
        float g0 = grads[(c * MTOT + jj) * 3 + 0];
        float g1 = grads[(c * MTOT + jj) * 3 + 1];
        float g2 = grads[(c * MTOT + jj) * 3 + 2];
        s_l1j[k][c][0] = g0; s_l1j[k][c][1] = g1; s_l1j[k][c][2] = g2;
        s_kin[k][96 + c] = g0 * s_dir[k][0] + g1 * s_dir[k][1] + g2 * s_dir[k][2];
    }
    if (lane < KNN) s_kin[lane][99] = 0.0f;
    __syncthreads();

    // ---- edge embedding -> kin[:, 64:96] ----
    for (int f = lane; f < KNN * EDGE_; f += 64) {
        int k = f >> 5, d = f & 31;
        float acc = be[d] + We[(RBF_ + s_bc[k]) * EDGE_ + d];
        #pragma unroll
        for (int r = 0; r < RBF_; ++r) acc += s_rbf[k][r] * We[r * EDGE_ + d];
        s_kin[k][64 + d] = acc;
    }
    // ---- fold q into Wk: qW[h][c] = sum_d q[h,d] * Wk[c, h*16+d] ----
    for (int t = 0; t < 7; ++t) {
        int c = t * 16 + l15;
        if (c < 99) {
            const float* wk = &Wk[c * 64 + h * 16];
            float acc = 0.0f;
            #pragma unroll
            for (int d = 0; d < 16; ++d) acc += s_q[h * 16 + d] * wk[d];
            s_qw[h][c] = acc;
        }
    }
    __syncthreads();

    // ---- logits[h][k] = kin[k] . qW[h] ----
    for (int f = lane; f < 96; f += 64) {
        int k = f >> 2, hh = f & 3;
        const float4* k4 = (const float4*)s_kin[k];
        const float4* q4 = (const float4*)s_qw[hh];
        float acc = 0.0f;
        #pragma unroll
        for (int c4 = 0; c4 < 24; ++c4) {
            float4 a = k4[c4], b = q4[c4];
            acc += a.x * b.x + a.y * b.y + a.z * b.z + a.w * b.w;
        }
        acc += s_kin[k][96] * s_qw[hh][96] + s_kin[k][97] * s_qw[hh][97]
             + s_kin[k][98] * s_qw[hh][98];
        s_logit[hh][k] = s_ok[k] ? acc * 0.25f : -1e9f;
    }
    __syncthreads();

    // ---- softmax ----
    float attn[KNN];
    {
        float mx = -1e30f;
        #pragma unroll
        for (int k = 0; k < KNN; ++k) { attn[k] = s_logit[h][k]; mx = fmaxf(mx, attn[k]); }
        float ss = 0.0f;
        #pragma unroll
        for (int k = 0; k < KNN; ++k) { attn[k] = expf(attn[k] - mx); ss += attn[k]; }
        float rs = 1.0f / ss;
        #pragma unroll
        for (int k = 0; k < KNN; ++k) attn[k] *= rs;
    }
    s_attn[h][l15] = attn[l15];
    if (l15 < 8) s_attn[h][16 + l15] = attn[16 + l15];

    // ---- wkin[h][c] = sum_k attn[k] * kin[k][c] ----
    for (int t = 0; t < 7; ++t) {
        int c = t * 16 + l15;
        if (c < 99) {
            float acc = 0.0f;
            #pragma unroll
            for (int k = 0; k < KNN; ++k) acc += attn[k] * s_kin[k][c];
            s_wkin[h][c] = acc;
        }
    }
    // ---- v1[k][u] = kin[k] . Wv1[:,u] ----
    for (int t = 0; t < 6; ++t) {
        int k = (t * 64 + lane) >> 4;
        const float4* k4 = (const float4*)s_kin[k];
        const float* wv = &Wv1[l15];
        float acc = 0.0f;
        #pragma unroll
        for (int c4 = 0; c4 < 24; ++c4) {
            float4 a = k4[c4];
            acc += a.x * wv[(c4 * 4 + 0) * 16] + a.y * wv[(c4 * 4 + 1) * 16]
                 + a.z * wv[(c4 * 4 + 2) * 16] + a.w * wv[(c4 * 4 + 3) * 16];
        }
        acc += s_kin[k][96] * wv[96 * 16] + s_kin[k][97] * wv[97 * 16]
             + s_kin[k][98] * wv[98 * 16];
        s_v1[k][l15] = acc;
    }
    __syncthreads();

    // ---- o0[lane] = sum_c wkin[h][c] * Wv0[c, lane] ----
    {
        float o0 = 0.0f;
        for (int c = 0; c < 99; ++c) o0 += s_wkin[h][c] * Wv0[c * 64 + lane];
        s_o0[lane] = o0;
    }
    __syncthreads();

    // ---- out0 = o0 @ Wo0 + node0 @ Wself + b0 ----
    {
        float acc = b0[lane];
        for (int t = 0; t < 64; ++t) acc += s_o0[t] * Wo0[t * 64 + lane];
        for (int t = 0; t < 64; ++t) acc += s_qin[t] * Wself[t * 64 + lane];
        out_state[i * D0_ + lane] = acc;
    }
    // ---- coef[k][c] = sum_h attn[h][k] * v1[k][h*4+c] ----
    for (int f = lane; f < KNN * 4; f += 64) {
        int k = f >> 2, c = f & 3;
        float a2 = 0.0f;
        #pragma unroll
        for (int hh = 0; hh < 4; ++hh) a2 += s_attn[hh][k] * s_v1[k][hh * 4 + c];
        s_coef[k][c] = a2;
    }
    __syncthreads();

    // ---- vector message -> xyz shift ----
    if (lane < 3) {
        float o1 = 0.0f;
        #pragma unroll
        for (int k = 0; k < KNN; ++k) {
            float t = s_coef[k][0] * s_dir[k][lane];
            t += s_coef[k][1] * s_l1j[k][0][lane];
            t += s_coef[k][2] * s_l1j[k][1][lane];
            t += s_coef[k][3] * s_l1j[k][2][lane];
            o1 += t;
        }
        out_xyz[i * 3 + lane] = s_xi[lane] + o1 / 100.0f;
    }
}

extern "C" void kernel_launch(void* const* d_in, const int* in_sizes, int n_in,
                              void* d_out, int out_size, void* d_ws, size_t ws_size,
                              hipStream_t stream) {
    const int*   seq    = (const int*)d_in[0];
    const float* xyz    = (const float*)d_in[1];
    const int*   aamask = (const int*)d_in[2];
    const int*   nbonds = (const int*)d_in[3];
    const float* state  = (const float*)d_in[4];
    const float* grads  = (const float*)d_in[5];
    const float* We    = (const float*)d_in[7];
    const float* be    = (const float*)d_in[8];
    const float* Wq    = (const float*)d_in[9];
    const float* Wk    = (const float*)d_in[10];
    const float* Wv0   = (const float*)d_in[11];
    const float* Wv1   = (const float*)d_in[12];
    const float* Wo0   = (const float*)d_in[13];
    const float* Wself = (const float*)d_in[14];
    const float* b0    = (const float*)d_in[15];

    float* out_xyz   = (float*)d_out;
    float* out_state = out_xyz + MTOT * 3;

    char* ws = (char*)d_ws;
    int*    cnt  = (int*)ws;                              // 16 B
    float4* pact = (float4*)(ws + 16);                    // (MTOT+256)*16 = 151552 B
    int*    idx  = (int*)(ws + 16 + 151552);              // 884736 B

    hipMemsetAsync(cnt, 0, 16, stream);
    k_prep<<<(MTOT * D0_ / 4 + 255) / 256, 256, 0, stream>>>(
        seq, xyz, aamask, (const float4*)state, (float4*)out_state,
        pact, out_xyz, cnt);
    k_nbr<<<(MTOT + WPB - 1) / WPB, WPB * 64, 0, stream>>>(pact, cnt, idx);
    k_attn<<<MTOT, 64, 0, stream>>>(xyz, seq, nbonds, state, grads, We, be, Wq, Wk,
                                    Wv0, Wv1, Wo0, Wself, b0, pact, cnt, idx,
                                    out_xyz, out_state);
}

// Round 3
// 194.984 us; speedup vs baseline: 1.1481x; 1.0859x over previous
//
#include <hip/hip_runtime.h>
#include <math.h>

#define MTOT 9216
#define A_ 36
#define D0_ 64
#define EDGE_ 32
#define RBF_ 16
#define KNN 24
#define QIN_ 67    // D0 + KC
#define EPS_ 1e-5f

// ---- prep: state passthrough copy + pact build + xyz passthrough (fused) ----
__global__ void k_prep(const int* __restrict__ seq, const float* __restrict__ xyz,
                       const int* __restrict__ aamask,
                       const float4* __restrict__ state4, float4* __restrict__ out_state4,
                       float4* __restrict__ pact, float* __restrict__ out_xyz,
                       int* __restrict__ cnt) {
    int t = blockIdx.x * blockDim.x + threadIdx.x;
    if (t < MTOT * D0_ / 4) out_state4[t] = state4[t];
    if (t < MTOT) {
        int r = t / A_;
        int a = t - r * A_;
        int mk = (aamask[seq[r] * A_ + a] != 0);
        float x0 = xyz[t * 3 + 0], x1 = xyz[t * 3 + 1], x2 = xyz[t * 3 + 2];
        out_xyz[t * 3 + 0] = x0;
        out_xyz[t * 3 + 1] = x1;
        out_xyz[t * 3 + 2] = x2;
        if (mk) {
            int p = atomicAdd(cnt, 1);   // compiler wave-aggregates
            pact[p] = make_float4(x0, x1, x2, __int_as_float(t));
        }
    }
}

// ------- exact top-24, wave-per-atom, lane-parallel histogram (VALU-only),
// ------- mantissa-refined candidate filter + unrolled rank-select ----------
#define CAPN 256
#define WPB 2
#define UNR 4
#define CHUNK (64 * UNR)

__global__ __launch_bounds__(128) void k_nbr(const float4* __restrict__ pact,
                                             const int* __restrict__ cnt,
                                             int* __restrict__ idx) {
    __shared__ uint2 s_cand[WPB][CAPN];       // coarse-filtered candidates
    __shared__ uint2 s_cand2[WPB][CAPN + 4];  // refined candidates (+pad)

    const int nact = *cnt;
    const int lane = threadIdx.x & 63;
    const int wv = threadIdx.x >> 6;
    const int slot = blockIdx.x * WPB + wv;
    if (slot >= nact) return;            // wave-uniform exit; no block barriers

    const float4 pq = pact[slot];
    const int ia = __float_as_int(pq.w);
    const unsigned long long lmask = (1ULL << lane) - 1ULL;

    // prefetch helper: wave-uniform clamped base (chunk-0 dummy when OOB;
    // pact padded by 256 entries so all lanes stay in-bounds)
    auto pre = [&](float4* p, int base) {
        int b2 = (base < nact) ? base : 0;
        #pragma unroll
        for (int u = 0; u < UNR; ++u) p[u] = pact[b2 + u * 64 + lane];
    };

    // ---- pass A: cumulative histogram, 16 raw-bits thresholds (exp bins) ----
    unsigned cum[16];
    #pragma unroll
    for (int b = 0; b < 16; ++b) cum[b] = 0u;

    auto histo = [&](const float4* p, int base) {
        #pragma unroll
        for (int u = 0; u < UNR; ++u) {
            int c = base + u * 64 + lane;
            int j = __float_as_int(p[u].w);
            float dx = p[u].x - pq.x, dy = p[u].y - pq.y, dz = p[u].z - pq.z;
            float d2 = dx * dx + dy * dy + dz * dz;
            unsigned bt = (c < nact && j != ia) ? __float_as_uint(d2) : 0xFFFFFFFFu;
            #pragma unroll
            for (int b = 0; b < 16; ++b) {
                const unsigned L = (unsigned)(242 + 2 * b) << 22;   // == exp < 121+b
                cum[b] += (bt < L) ? 1u : 0u;
            }
        }
    };

    float4 pA[UNR], pB[UNR];
    pre(pA, 0);
    for (int base = 0; base < nact; base += 2 * CHUNK) {
        pre(pB, base + CHUNK);
        histo(pA, base);
        pre(pA, base + 2 * CHUNK);
        if (base + CHUNK < nact) histo(pB, base + CHUNK);
    }

    // wave-wide butterfly reduce; every lane ends with the full-wave totals
    #pragma unroll
    for (int b = 0; b < 16; ++b) {
        unsigned v = cum[b];
        #pragma unroll
        for (int off = 32; off > 0; off >>= 1)
            v += (unsigned)__shfl_xor((int)v, off, 64);
        cum[b] = v;
    }

    // ---- threshold of the 24th smallest (uniform across lanes) ----
    int bsel = 15;
    #pragma unroll
    for (int b = 15; b >= 0; --b) if (cum[b] >= KNN) bsel = b;
    const unsigned limit = (unsigned)(242 + 2 * bsel) << 22;

    // ---- pass B: ballot-compacted candidate collection (superset of top-24) ----
    int nsel = 0;
    auto collect = [&](const float4* p, int base) {
        #pragma unroll
        for (int u = 0; u < UNR; ++u) {
            int c = base + u * 64 + lane;
            int j = __float_as_int(p[u].w);
            float dx = p[u].x - pq.x, dy = p[u].y - pq.y, dz = p[u].z - pq.z;
            float d2 = dx * dx + dy * dy + dz * dz;
            unsigned bits = (c < nact && j != ia) ? __float_as_uint(d2) : 0xFFFFFFFFu;
            bool sel = bits < limit;
            unsigned long long m = __ballot(sel);
            int pos = nsel + (int)__popcll(m & lmask);
            if (sel && pos < CAPN) s_cand[wv][pos] = make_uint2(bits, (unsigned)j);
            nsel += (int)__popcll(m);
        }
    };

    pre(pA, 0);
    for (int base = 0; base < nact; base += 2 * CHUNK) {
        pre(pB, base + CHUNK);
        collect(pA, base);
        pre(pA, base + 2 * CHUNK);
        if (base + CHUNK < nact) collect(pB, base + CHUNK);
    }
    __builtin_amdgcn_wave_barrier();

    // ---- refinement: subdivide the selected coarse bin by top-4 mantissa ----
    // bins are quartic in d^2 so nsel ~ 8x KNN; the serial rank loop over it
    // was the latency hot spot. Shrink the set to ~24-44 first.
    const int n = min(nsel, CAPN);
    uint2 r0 = s_cand[wv][lane];
    uint2 r1 = s_cand[wv][lane + 64];
    uint2 r2 = s_cand[wv][lane + 128];
    uint2 r3 = s_cand[wv][lane + 192];
    const uint2 inval = make_uint2(0xFFFFFFFFu, 0xFFFFFFFFu);
    if (lane >= n)       r0 = inval;
    if (lane + 64 >= n)  r1 = inval;
    if (lane + 128 >= n) r2 = inval;
    if (lane + 192 >= n) r3 = inval;

    const unsigned prev = limit - (1u << 23);   // lower edge of selected bin
    unsigned c2r[16];
    #pragma unroll
    for (int m = 0; m < 16; ++m) {
        const unsigned T = prev + ((unsigned)(m + 1) << 19);
        unsigned s = (r0.x < T) ? 1u : 0u;
        s += (r1.x < T) ? 1u : 0u;
        s += (r2.x < T) ? 1u : 0u;
        s += (r3.x < T) ? 1u : 0u;
        c2r[m] = s;
    }
    #pragma unroll
    for (int m = 0; m < 16; ++m) {
        unsigned v = c2r[m];
        #pragma unroll
        for (int off = 32; off > 0; off >>= 1)
            v += (unsigned)__shfl_xor((int)v, off, 64);
        c2r[m] = v;
    }
    int msel = 15;
    #pragma unroll
    for (int m = 15; m >= 0; --m) if (c2r[m] >= KNN) msel = m;
    const unsigned limit2 = prev + ((unsigned)(msel + 1) << 19);
    // correctness: count(key < limit2) >= KNN (c2r[15] == n >= KNN); filtering
    // by key < limit2 preserves exact global ranks of survivors (any o < my
    // has o.x <= my.x < limit2, so every comparator survives too).

    // ---- compact refined set ----
    int nsel2 = 0;
    {
        #pragma unroll
        for (int t = 0; t < 4; ++t) {
            uint2 r = (t == 0) ? r0 : (t == 1) ? r1 : (t == 2) ? r2 : r3;
            bool sel = r.x < limit2;
            unsigned long long m = __ballot(sel);
            int pos = nsel2 + (int)__popcll(m & lmask);
            if (sel && pos < CAPN) s_cand2[wv][pos] = r;
            nsel2 += (int)__popcll(m);
        }
    }
    __builtin_amdgcn_wave_barrier();

    const int n2 = min(nsel2, CAPN);
    if (lane < 4) s_cand2[wv][n2 + lane] = inval;   // x4 sentinel pad
    __builtin_amdgcn_wave_barrier();

    // ---- exact rank select, 4-wide unrolled ((d2, j) lex == lax.top_k) ----
    const int n2r = (n2 + 3) & ~3;
    for (int c = lane; c < n2; c += 64) {
        uint2 my = s_cand2[wv][c];
        int rank = 0;
        for (int c2 = 0; c2 < n2r; c2 += 4) {
            #pragma unroll
            for (int q = 0; q < 4; ++q) {
                uint2 o = s_cand2[wv][c2 + q];
                rank += (o.x < my.x || (o.x == my.x && o.y < my.y)) ? 1 : 0;
            }
        }
        if (rank < KNN) idx[ia * KNN + rank] = (int)my.y;
    }
}

// ---------------- per-atom attention, rank-reduced (R3 kernel, verbatim) -------
__global__ __launch_bounds__(64, 2) void k_attn(
    const float* __restrict__ xyz, const int* __restrict__ seq,
    const int* __restrict__ num_bonds, const float* __restrict__ state,
    const float* __restrict__ grads,
    const float* __restrict__ We, const float* __restrict__ be,
    const float* __restrict__ Wq, const float* __restrict__ Wk,
    const float* __restrict__ Wv0, const float* __restrict__ Wv1,
    const float* __restrict__ Wo0, const float* __restrict__ Wself,
    const float* __restrict__ b0,
    const float4* __restrict__ pact, const int* __restrict__ cnt,
    const int* __restrict__ idxbuf,
    float* __restrict__ out_xyz, float* __restrict__ out_state) {
    const int nact = *cnt;
    if ((int)blockIdx.x >= nact) return;
    const int i = __float_as_int(pact[blockIdx.x].w);
    const int lane = threadIdx.x;
    const int l15 = lane & 15;
    const int h = lane >> 4;

    __shared__ float s_kin[KNN][100];   // [node0(64) | e(32) | inv(3) | pad]
    __shared__ float s_qw[4][100];      // Wk folded with q, per head
    __shared__ float s_wkin[4][100];    // attn-weighted kin, per head
    __shared__ float s_dir[KNN][4];
    __shared__ float s_rbf[KNN][RBF_];
    __shared__ float s_l1j[KNN][3][3];
    __shared__ float s_qin[68];
    __shared__ float s_q[64];
    __shared__ float s_logit[4][KNN];
    __shared__ float s_attn[4][KNN];
    __shared__ float s_o0[64];
    __shared__ float s_v1[KNN][16];
    __shared__ float s_coef[KNN][4];
    __shared__ int   s_j[KNN];
    __shared__ int   s_ok[KNN];
    __shared__ int   s_bc[KNN];
    __shared__ float s_xi[3];

    // ---- stage per-atom inputs ----
    s_qin[lane] = state[i * D0_ + lane];
    if (lane < 3) {
        float g0 = grads[(lane * MTOT + i) * 3 + 0];
        float g1 = grads[(lane * MTOT + i) * 3 + 1];
        float g2 = grads[(lane * MTOT + i) * 3 + 2];
        s_qin[D0_ + lane] = sqrtf(g0 * g0 + g1 * g1 + g2 * g2 + EPS_);
        s_xi[lane] = xyz[i * 3 + lane];
    }
    if (lane < KNN) {
        int j = idxbuf[i * KNN + lane];
        int ok = (j >= 0 && j < MTOT);
        int jj = ok ? j : 0;
        s_j[lane] = jj;
        s_ok[lane] = ok;
        float dx = xyz[jj * 3 + 0] - xyz[i * 3 + 0];
        float dy = xyz[jj * 3 + 1] - xyz[i * 3 + 1];
        float dz = xyz[jj * 3 + 2] - xyz[i * 3 + 2];
        float dist = sqrtf(dx * dx + dy * dy + dz * dz + EPS_);
        s_dir[lane][0] = dx / dist;
        s_dir[lane][1] = dy / dist;
        s_dir[lane][2] = dz / dist;
        s_dir[lane][3] = dist;
        int ri = i / A_, ai = i - ri * A_;
        int rj = jj / A_, aj = jj - rj * A_;
        int b = 0;
        if (rj == ri) b = num_bonds[(seq[ri] * A_ + ai) * A_ + aj];
        s_bc[lane] = min(max(b, 0), 4);
    }
    __syncthreads();

    // ---- q projection ----
    {
        float q = 0.0f;
        for (int c = 0; c < QIN_; ++c) q += s_qin[c] * Wq[c * 64 + lane];
        s_q[lane] = q;
    }
    // ---- rbf ----
    for (int f = lane; f < KNN * RBF_; f += 64) {
        int k = f >> 4, r = f & 15;
        float mu = (6.0f / 15.0f) * (float)r;
        float d = s_dir[k][3] - mu;
        s_rbf[k][r] = expf(-d * d * 2.0f);
    }
    // ---- neighbor node0 gather ----
    for (int k = 0; k < KNN; ++k) s_kin[k][lane] = state[s_j[k] * D0_ + lane];
    // ---- l1 invariants + stash l1j ----
    for (int f = lane; f < KNN * 3; f += 64) {
        int k = f / 3, c = f - 3 * k;
        int jj = s_j[k];
        float g0 = grads[(c * MTOT + jj) * 3 + 0];
        float g1 = grads[(c * MTOT + jj) * 3 + 1];
        float g2 = grads[(c * MTOT + jj) * 3 + 2];
        s_l1j[k][c][0] = g0; s_l1j[k][c][1] = g1; s_l1j[k][c][2] = g2;
        s_kin[k][96 + c] = g0 * s_dir[k][0] + g1 * s_dir[k][1] + g2 * s_dir[k][2];
    }
    if (lane < KNN) s_kin[lane][99] = 0.0f;
    __syncthreads();

    // ---- edge embedding -> kin[:, 64:96] ----
    for (int f = lane; f < KNN * EDGE_; f += 64) {
        int k = f >> 5, d = f & 31;
        float acc = be[d] + We[(RBF_ + s_bc[k]) * EDGE_ + d];
        #pragma unroll
        for (int r = 0; r < RBF_; ++r) acc += s_rbf[k][r] * We[r * EDGE_ + d];
        s_kin[k][64 + d] = acc;
    }
    // ---- fold q into Wk: qW[h][c] = sum_d q[h,d] * Wk[c, h*16+d] ----
    for (int t = 0; t < 7; ++t) {
        int c = t * 16 + l15;
        if (c < 99) {
            const float* wk = &Wk[c * 64 + h * 16];
            float acc = 0.0f;
            #pragma unroll
            for (int d = 0; d < 16; ++d) acc += s_q[h * 16 + d] * wk[d];
            s_qw[h][c] = acc;
        }
    }
    __syncthreads();

    // ---- logits[h][k] = kin[k] . qW[h] ----
    for (int f = lane; f < 96; f += 64) {
        int k = f >> 2, hh = f & 3;
        const float4* k4 = (const float4*)s_kin[k];
        const float4* q4 = (const float4*)s_qw[hh];
        float acc = 0.0f;
        #pragma unroll
        for (int c4 = 0; c4 < 24; ++c4) {
            float4 a = k4[c4], b = q4[c4];
            acc += a.x * b.x + a.y * b.y + a.z * b.z + a.w * b.w;
        }
        acc += s_kin[k][96] * s_qw[hh][96] + s_kin[k][97] * s_qw[hh][97]
             + s_kin[k][98] * s_qw[hh][98];
        s_logit[hh][k] = s_ok[k] ? acc * 0.25f : -1e9f;
    }
    __syncthreads();

    // ---- softmax ----
    float attn[KNN];
    {
        float mx = -1e30f;
        #pragma unroll
        for (int k = 0; k < KNN; ++k) { attn[k] = s_logit[h][k]; mx = fmaxf(mx, attn[k]); }
        float ss = 0.0f;
        #pragma unroll
        for (int k = 0; k < KNN; ++k) { attn[k] = expf(attn[k] - mx); ss += attn[k]; }
        float rs = 1.0f / ss;
        #pragma unroll
        for (int k = 0; k < KNN; ++k) attn[k] *= rs;
    }
    s_attn[h][l15] = attn[l15];
    if (l15 < 8) s_attn[h][16 + l15] = attn[16 + l15];

    // ---- wkin[h][c] = sum_k attn[k] * kin[k][c] ----
    for (int t = 0; t < 7; ++t) {
        int c = t * 16 + l15;
        if (c < 99) {
            float acc = 0.0f;
            #pragma unroll
            for (int k = 0; k < KNN; ++k) acc += attn[k] * s_kin[k][c];
            s_wkin[h][c] = acc;
        }
    }
    // ---- v1[k][u] = kin[k] . Wv1[:,u] ----
    for (int t = 0; t < 6; ++t) {
        int k = (t * 64 + lane) >> 4;
        const float4* k4 = (const float4*)s_kin[k];
        const float* wv = &Wv1[l15];
        float acc = 0.0f;
        #pragma unroll
        for (int c4 = 0; c4 < 24; ++c4) {
            float4 a = k4[c4];
            acc += a.x * wv[(c4 * 4 + 0) * 16] + a.y * wv[(c4 * 4 + 1) * 16]
                 + a.z * wv[(c4 * 4 + 2) * 16] + a.w * wv[(c4 * 4 + 3) * 16];
        }
        acc += s_kin[k][96] * wv[96 * 16] + s_kin[k][97] * wv[97 * 16]
             + s_kin[k][98] * wv[98 * 16];
        s_v1[k][l15] = acc;
    }
    __syncthreads();

    // ---- o0[lane] = sum_c wkin[h][c] * Wv0[c, lane] ----
    {
        float o0 = 0.0f;
        for (int c = 0; c < 99; ++c) o0 += s_wkin[h][c] * Wv0[c * 64 + lane];
        s_o0[lane] = o0;
    }
    __syncthreads();

    // ---- out0 = o0 @ Wo0 + node0 @ Wself + b0 ----
    {
        float acc = b0[lane];
        for (int t = 0; t < 64; ++t) acc += s_o0[t] * Wo0[t * 64 + lane];
        for (int t = 0; t < 64; ++t) acc += s_qin[t] * Wself[t * 64 + lane];
        out_state[i * D0_ + lane] = acc;
    }
    // ---- coef[k][c] = sum_h attn[h][k] * v1[k][h*4+c] ----
    for (int f = lane; f < KNN * 4; f += 64) {
        int k = f >> 2, c = f & 3;
        float a2 = 0.0f;
        #pragma unroll
        for (int hh = 0; hh < 4; ++hh) a2 += s_attn[hh][k] * s_v1[k][hh * 4 + c];
        s_coef[k][c] = a2;
    }
    __syncthreads();

    // ---- vector message -> xyz shift ----
    if (lane < 3) {
        float o1 = 0.0f;
        #pragma unroll
        for (int k = 0; k < KNN; ++k) {
            float t = s_coef[k][0] * s_dir[k][lane];
            t += s_coef[k][1] * s_l1j[k][0][lane];
            t += s_coef[k][2] * s_l1j[k][1][lane];
            t += s_coef[k][3] * s_l1j[k][2][lane];
            o1 += t;
        }
        out_xyz[i * 3 + lane] = s_xi[lane] + o1 / 100.0f;
    }
}

extern "C" void kernel_launch(void* const* d_in, const int* in_sizes, int n_in,
                              void* d_out, int out_size, void* d_ws, size_t ws_size,
                              hipStream_t stream) {
    const int*   seq    = (const int*)d_in[0];
    const float* xyz    = (const float*)d_in[1];
    const int*   aamask = (const int*)d_in[2];
    const int*   nbonds = (const int*)d_in[3];
    const float* state  = (const float*)d_in[4];
    const float* grads  = (const float*)d_in[5];
    const float* We    = (const float*)d_in[7];
    const float* be    = (const float*)d_in[8];
    const float* Wq    = (const float*)d_in[9];
    const float* Wk    = (const float*)d_in[10];
    const float* Wv0   = (const float*)d_in[11];
    const float* Wv1   = (const float*)d_in[12];
    const float* Wo0   = (const float*)d_in[13];
    const float* Wself = (const float*)d_in[14];
    const float* b0    = (const float*)d_in[15];

    float* out_xyz   = (float*)d_out;
    float* out_state = out_xyz + MTOT * 3;

    char* ws = (char*)d_ws;
    int*    cnt  = (int*)ws;                              // 16 B
    float4* pact = (float4*)(ws + 16);                    // (MTOT+256)*16 = 151552 B
    int*    idx  = (int*)(ws + 16 + 151552);              // 884736 B

    hipMemsetAsync(cnt, 0, 16, stream);
    k_prep<<<(MTOT * D0_ / 4 + 255) / 256, 256, 0, stream>>>(
        seq, xyz, aamask, (const float4*)state, (float4*)out_state,
        pact, out_xyz, cnt);
    k_nbr<<<(MTOT + WPB - 1) / WPB, WPB * 64, 0, stream>>>(pact, cnt, idx);
    k_attn<<<MTOT, 64, 0, stream>>>(xyz, seq, nbonds, state, grads, We, be, Wq, Wk,
                                    Wv0, Wv1, Wo0, Wself, b0, pact, cnt, idx,
                                    out_xyz, out_state);
}

// Round 4
// 192.378 us; speedup vs baseline: 1.1636x; 1.0135x over previous
//
#include <hip/hip_runtime.h>
#include <math.h>

#define MTOT 9216
#define A_ 36
#define D0_ 64
#define EDGE_ 32
#define RBF_ 16
#define KNN 24
#define QIN_ 67    // D0 + KC
#define EPS_ 1e-5f

// ---- prep: state passthrough copy + pact build + xyz passthrough (fused) ----
__global__ void k_prep(const int* __restrict__ seq, const float* __restrict__ xyz,
                       const int* __restrict__ aamask,
                       const float4* __restrict__ state4, float4* __restrict__ out_state4,
                       float4* __restrict__ pact, float* __restrict__ out_xyz,
                       int* __restrict__ cnt) {
    int t = blockIdx.x * blockDim.x + threadIdx.x;
    if (t < MTOT * D0_ / 4) out_state4[t] = state4[t];
    if (t < MTOT) {
        int r = t / A_;
        int a = t - r * A_;
        int mk = (aamask[seq[r] * A_ + a] != 0);
        float x0 = xyz[t * 3 + 0], x1 = xyz[t * 3 + 1], x2 = xyz[t * 3 + 2];
        out_xyz[t * 3 + 0] = x0;
        out_xyz[t * 3 + 1] = x1;
        out_xyz[t * 3 + 2] = x2;
        if (mk) {
            int p = atomicAdd(cnt, 1);   // compiler wave-aggregates
            pact[p] = make_float4(x0, x1, x2, __int_as_float(t));
        }
    }
}

// ------- exact top-24, wave-per-atom, lane-parallel histogram (VALU-only),
// ------- mantissa-refined candidate filter + unrolled rank-select ----------
#define CAPN 256
#define WPB 2
#define UNR 4
#define CHUNK (64 * UNR)

__global__ __launch_bounds__(128) void k_nbr(const float4* __restrict__ pact,
                                             const int* __restrict__ cnt,
                                             int* __restrict__ idx) {
    __shared__ uint2 s_cand[WPB][CAPN];       // coarse-filtered candidates
    __shared__ uint2 s_cand2[WPB][CAPN + 4];  // refined candidates (+pad)

    const int nact = *cnt;
    const int lane = threadIdx.x & 63;
    const int wv = threadIdx.x >> 6;
    const int slot = blockIdx.x * WPB + wv;
    if (slot >= nact) return;            // wave-uniform exit; no block barriers

    const float4 pq = pact[slot];
    const int ia = __float_as_int(pq.w);
    const unsigned long long lmask = (1ULL << lane) - 1ULL;

    // prefetch helper: wave-uniform clamped base (chunk-0 dummy when OOB;
    // pact padded by 256 entries so all lanes stay in-bounds)
    auto pre = [&](float4* p, int base) {
        int b2 = (base < nact) ? base : 0;
        #pragma unroll
        for (int u = 0; u < UNR; ++u) p[u] = pact[b2 + u * 64 + lane];
    };

    // ---- pass A: cumulative histogram, 16 raw-bits thresholds (exp bins) ----
    unsigned cum[16];
    #pragma unroll
    for (int b = 0; b < 16; ++b) cum[b] = 0u;

    auto histo = [&](const float4* p, int base) {
        #pragma unroll
        for (int u = 0; u < UNR; ++u) {
            int c = base + u * 64 + lane;
            int j = __float_as_int(p[u].w);
            float dx = p[u].x - pq.x, dy = p[u].y - pq.y, dz = p[u].z - pq.z;
            float d2 = dx * dx + dy * dy + dz * dz;
            unsigned bt = (c < nact && j != ia) ? __float_as_uint(d2) : 0xFFFFFFFFu;
            #pragma unroll
            for (int b = 0; b < 16; ++b) {
                const unsigned L = (unsigned)(242 + 2 * b) << 22;   // == exp < 121+b
                cum[b] += (bt < L) ? 1u : 0u;
            }
        }
    };

    float4 pA[UNR], pB[UNR];
    pre(pA, 0);
    for (int base = 0; base < nact; base += 2 * CHUNK) {
        pre(pB, base + CHUNK);
        histo(pA, base);
        pre(pA, base + 2 * CHUNK);
        if (base + CHUNK < nact) histo(pB, base + CHUNK);
    }

    // wave-wide butterfly reduce; every lane ends with the full-wave totals
    #pragma unroll
    for (int b = 0; b < 16; ++b) {
        unsigned v = cum[b];
        #pragma unroll
        for (int off = 32; off > 0; off >>= 1)
            v += (unsigned)__shfl_xor((int)v, off, 64);
        cum[b] = v;
    }

    // ---- threshold of the 24th smallest (uniform across lanes) ----
    int bsel = 15;
    #pragma unroll
    for (int b = 15; b >= 0; --b) if (cum[b] >= KNN) bsel = b;
    const unsigned limit = (unsigned)(242 + 2 * bsel) << 22;

    // ---- pass B: ballot-compacted candidate collection (superset of top-24) ----
    int nsel = 0;
    auto collect = [&](const float4* p, int base) {
        #pragma unroll
        for (int u = 0; u < UNR; ++u) {
            int c = base + u * 64 + lane;
            int j = __float_as_int(p[u].w);
            float dx = p[u].x - pq.x, dy = p[u].y - pq.y, dz = p[u].z - pq.z;
            float d2 = dx * dx + dy * dy + dz * dz;
            unsigned bits = (c < nact && j != ia) ? __float_as_uint(d2) : 0xFFFFFFFFu;
            bool sel = bits < limit;
            unsigned long long m = __ballot(sel);
            int pos = nsel + (int)__popcll(m & lmask);
            if (sel && pos < CAPN) s_cand[wv][pos] = make_uint2(bits, (unsigned)j);
            nsel += (int)__popcll(m);
        }
    };

    pre(pA, 0);
    for (int base = 0; base < nact; base += 2 * CHUNK) {
        pre(pB, base + CHUNK);
        collect(pA, base);
        pre(pA, base + 2 * CHUNK);
        if (base + CHUNK < nact) collect(pB, base + CHUNK);
    }
    __builtin_amdgcn_wave_barrier();

    // ---- refinement: subdivide the selected coarse bin by top-4 mantissa ----
    const int n = min(nsel, CAPN);
    uint2 r0 = s_cand[wv][lane];
    uint2 r1 = s_cand[wv][lane + 64];
    uint2 r2 = s_cand[wv][lane + 128];
    uint2 r3 = s_cand[wv][lane + 192];
    const uint2 inval = make_uint2(0xFFFFFFFFu, 0xFFFFFFFFu);
    if (lane >= n)       r0 = inval;
    if (lane + 64 >= n)  r1 = inval;
    if (lane + 128 >= n) r2 = inval;
    if (lane + 192 >= n) r3 = inval;

    const unsigned prev = limit - (1u << 23);   // lower edge of selected bin
    unsigned c2r[16];
    #pragma unroll
    for (int m = 0; m < 16; ++m) {
        const unsigned T = prev + ((unsigned)(m + 1) << 19);
        unsigned s = (r0.x < T) ? 1u : 0u;
        s += (r1.x < T) ? 1u : 0u;
        s += (r2.x < T) ? 1u : 0u;
        s += (r3.x < T) ? 1u : 0u;
        c2r[m] = s;
    }
    #pragma unroll
    for (int m = 0; m < 16; ++m) {
        unsigned v = c2r[m];
        #pragma unroll
        for (int off = 32; off > 0; off >>= 1)
            v += (unsigned)__shfl_xor((int)v, off, 64);
        c2r[m] = v;
    }
    int msel = 15;
    #pragma unroll
    for (int m = 15; m >= 0; --m) if (c2r[m] >= KNN) msel = m;
    const unsigned limit2 = prev + ((unsigned)(msel + 1) << 19);
    // correctness: count(key < limit2) >= KNN; filtering by key < limit2
    // preserves exact global ranks of survivors.

    // ---- compact refined set ----
    int nsel2 = 0;
    {
        #pragma unroll
        for (int t = 0; t < 4; ++t) {
            uint2 r = (t == 0) ? r0 : (t == 1) ? r1 : (t == 2) ? r2 : r3;
            bool sel = r.x < limit2;
            unsigned long long m = __ballot(sel);
            int pos = nsel2 + (int)__popcll(m & lmask);
            if (sel && pos < CAPN) s_cand2[wv][pos] = r;
            nsel2 += (int)__popcll(m);
        }
    }
    __builtin_amdgcn_wave_barrier();

    const int n2 = min(nsel2, CAPN);
    if (lane < 4) s_cand2[wv][n2 + lane] = inval;   // x4 sentinel pad
    __builtin_amdgcn_wave_barrier();

    // ---- exact rank select, 4-wide unrolled ((d2, j) lex == lax.top_k) ----
    const int n2r = (n2 + 3) & ~3;
    for (int c = lane; c < n2; c += 64) {
        uint2 my = s_cand2[wv][c];
        int rank = 0;
        for (int c2 = 0; c2 < n2r; c2 += 4) {
            #pragma unroll
            for (int q = 0; q < 4; ++q) {
                uint2 o = s_cand2[wv][c2 + q];
                rank += (o.x < my.x || (o.x == my.x && o.y < my.y)) ? 1 : 0;
            }
        }
        if (rank < KNN) idx[ia * KNN + rank] = (int)my.y;
    }
}

// ---------------- per-atom attention -------------------------------------
// Single-wave block: __syncthreads replaced with wave_barrier (code-motion
// barrier only — no vmcnt(0) drain, so weight loads pipeline across phases;
// DS ops within one wave are ordered, compiler inserts data waits).
// Long dot products split into 4 accumulators to break fmac dep chains.
#define WB() __builtin_amdgcn_wave_barrier()

__global__ __launch_bounds__(64, 2) void k_attn(
    const float* __restrict__ xyz, const int* __restrict__ seq,
    const int* __restrict__ num_bonds, const float* __restrict__ state,
    const float* __restrict__ grads,
    const float* __restrict__ We, const float* __restrict__ be,
    const float* __restrict__ Wq, const float* __restrict__ Wk,
    const float* __restrict__ Wv0, const float* __restrict__ Wv1,
    const float* __restrict__ Wo0, const float* __restrict__ Wself,
    const float* __restrict__ b0,
    const float4* __restrict__ pact, const int* __restrict__ cnt,
    const int* __restrict__ idxbuf,
    float* __restrict__ out_xyz, float* __restrict__ out_state) {
    const int nact = *cnt;
    if ((int)blockIdx.x >= nact) return;
    const int i = __float_as_int(pact[blockIdx.x].w);
    const int lane = threadIdx.x;
    const int l15 = lane & 15;
    const int h = lane >> 4;

    __shared__ float s_kin[KNN][100];   // [node0(64) | e(32) | inv(3) | pad]
    __shared__ float s_qw[4][100];      // Wk folded with q, per head
    __shared__ float s_wkin[4][100];    // attn-weighted kin, per head
    __shared__ float s_dir[KNN][4];
    __shared__ float s_rbf[KNN][RBF_];
    __shared__ float s_l1j[KNN][3][3];
    __shared__ float s_qin[68];
    __shared__ float s_q[64];
    __shared__ float s_logit[4][KNN];
    __shared__ float s_attn[4][KNN];
    __shared__ float s_o0[64];
    __shared__ float s_v1[KNN][16];
    __shared__ float s_coef[KNN][4];
    __shared__ int   s_j[KNN];
    __shared__ int   s_ok[KNN];
    __shared__ int   s_bc[KNN];
    __shared__ float s_xi[3];

    // ---- stage per-atom inputs ----
    s_qin[lane] = state[i * D0_ + lane];
    if (lane < 3) {
        float g0 = grads[(lane * MTOT + i) * 3 + 0];
        float g1 = grads[(lane * MTOT + i) * 3 + 1];
        float g2 = grads[(lane * MTOT + i) * 3 + 2];
        s_qin[D0_ + lane] = sqrtf(g0 * g0 + g1 * g1 + g2 * g2 + EPS_);
        s_xi[lane] = xyz[i * 3 + lane];
    }
    if (lane < KNN) {
        int j = idxbuf[i * KNN + lane];
        int ok = (j >= 0 && j < MTOT);
        int jj = ok ? j : 0;
        s_j[lane] = jj;
        s_ok[lane] = ok;
        float dx = xyz[jj * 3 + 0] - xyz[i * 3 + 0];
        float dy = xyz[jj * 3 + 1] - xyz[i * 3 + 1];
        float dz = xyz[jj * 3 + 2] - xyz[i * 3 + 2];
        float dist = sqrtf(dx * dx + dy * dy + dz * dz + EPS_);
        s_dir[lane][0] = dx / dist;
        s_dir[lane][1] = dy / dist;
        s_dir[lane][2] = dz / dist;
        s_dir[lane][3] = dist;
        int ri = i / A_, ai = i - ri * A_;
        int rj = jj / A_, aj = jj - rj * A_;
        int b = 0;
        if (rj == ri) b = num_bonds[(seq[ri] * A_ + ai) * A_ + aj];
        s_bc[lane] = min(max(b, 0), 4);
    }
    WB();

    // ---- q projection (4-acc) ----
    {
        float q0 = 0.0f, q1 = 0.0f, q2 = 0.0f, q3 = 0.0f;
        for (int c = 0; c < 64; c += 4) {
            q0 += s_qin[c + 0] * Wq[(c + 0) * 64 + lane];
            q1 += s_qin[c + 1] * Wq[(c + 1) * 64 + lane];
            q2 += s_qin[c + 2] * Wq[(c + 2) * 64 + lane];
            q3 += s_qin[c + 3] * Wq[(c + 3) * 64 + lane];
        }
        q0 += s_qin[64] * Wq[64 * 64 + lane];
        q1 += s_qin[65] * Wq[65 * 64 + lane];
        q2 += s_qin[66] * Wq[66 * 64 + lane];
        s_q[lane] = (q0 + q1) + (q2 + q3);
    }
    // ---- rbf ----
    for (int f = lane; f < KNN * RBF_; f += 64) {
        int k = f >> 4, r = f & 15;
        float mu = (6.0f / 15.0f) * (float)r;
        float d = s_dir[k][3] - mu;
        s_rbf[k][r] = expf(-d * d * 2.0f);
    }
    // ---- neighbor node0 gather ----
    for (int k = 0; k < KNN; ++k) s_kin[k][lane] = state[s_j[k] * D0_ + lane];
    // ---- l1 invariants + stash l1j ----
    for (int f = lane; f < KNN * 3; f += 64) {
        int k = f / 3, c = f - 3 * k;
        int jj = s_j[k];
        float g0 = grads[(c * MTOT + jj) * 3 + 0];
        float g1 = grads[(c * MTOT + jj) * 3 + 1];
        float g2 = grads[(c * MTOT + jj) * 3 + 2];
        s_l1j[k][c][0] = g0; s_l1j[k][c][1] = g1; s_l1j[k][c][2] = g2;
        s_kin[k][96 + c] = g0 * s_dir[k][0] + g1 * s_dir[k][1] + g2 * s_dir[k][2];
    }
    if (lane < KNN) s_kin[lane][99] = 0.0f;
    WB();

    // ---- edge embedding -> kin[:, 64:96] (2-acc) ----
    for (int f = lane; f < KNN * EDGE_; f += 64) {
        int k = f >> 5, d = f & 31;
        float e0 = be[d] + We[(RBF_ + s_bc[k]) * EDGE_ + d];
        float e1 = 0.0f;
        #pragma unroll
        for (int r = 0; r < RBF_; r += 2) {
            e0 += s_rbf[k][r] * We[r * EDGE_ + d];
            e1 += s_rbf[k][r + 1] * We[(r + 1) * EDGE_ + d];
        }
        s_kin[k][64 + d] = e0 + e1;
    }
    // ---- fold q into Wk: qW[h][c] = sum_d q[h,d] * Wk[c, h*16+d] (2-acc) ----
    for (int t = 0; t < 7; ++t) {
        int c = t * 16 + l15;
        if (c < 99) {
            const float* wk = &Wk[c * 64 + h * 16];
            float a0 = 0.0f, a1 = 0.0f;
            #pragma unroll
            for (int d = 0; d < 16; d += 2) {
                a0 += s_q[h * 16 + d] * wk[d];
                a1 += s_q[h * 16 + d + 1] * wk[d + 1];
            }
            s_qw[h][c] = a0 + a1;
        }
    }
    WB();

    // ---- logits[h][k] = kin[k] . qW[h] (4-acc) ----
    for (int f = lane; f < 96; f += 64) {
        int k = f >> 2, hh = f & 3;
        const float4* k4 = (const float4*)s_kin[k];
        const float4* q4 = (const float4*)s_qw[hh];
        float a0 = 0.0f, a1 = 0.0f, a2 = 0.0f, a3 = 0.0f;
        #pragma unroll
        for (int c4 = 0; c4 < 24; c4 += 4) {
            float4 x0 = k4[c4 + 0], y0 = q4[c4 + 0];
            a0 += x0.x * y0.x + x0.y * y0.y + x0.z * y0.z + x0.w * y0.w;
            float4 x1 = k4[c4 + 1], y1 = q4[c4 + 1];
            a1 += x1.x * y1.x + x1.y * y1.y + x1.z * y1.z + x1.w * y1.w;
            float4 x2 = k4[c4 + 2], y2 = q4[c4 + 2];
            a2 += x2.x * y2.x + x2.y * y2.y + x2.z * y2.z + x2.w * y2.w;
            float4 x3 = k4[c4 + 3], y3 = q4[c4 + 3];
            a3 += x3.x * y3.x + x3.y * y3.y + x3.z * y3.z + x3.w * y3.w;
        }
        float acc = (a0 + a1) + (a2 + a3);
        acc += s_kin[k][96] * s_qw[hh][96] + s_kin[k][97] * s_qw[hh][97]
             + s_kin[k][98] * s_qw[hh][98];
        s_logit[hh][k] = s_ok[k] ? acc * 0.25f : -1e9f;
    }
    WB();

    // ---- softmax ----
    float attn[KNN];
    {
        float mx = -1e30f;
        #pragma unroll
        for (int k = 0; k < KNN; ++k) { attn[k] = s_logit[h][k]; mx = fmaxf(mx, attn[k]); }
        float s0 = 0.0f, s1 = 0.0f, s2 = 0.0f, s3 = 0.0f;
        #pragma unroll
        for (int k = 0; k < KNN; k += 4) {
            attn[k + 0] = expf(attn[k + 0] - mx); s0 += attn[k + 0];
            attn[k + 1] = expf(attn[k + 1] - mx); s1 += attn[k + 1];
            attn[k + 2] = expf(attn[k + 2] - mx); s2 += attn[k + 2];
            attn[k + 3] = expf(attn[k + 3] - mx); s3 += attn[k + 3];
        }
        float rs = 1.0f / ((s0 + s1) + (s2 + s3));
        #pragma unroll
        for (int k = 0; k < KNN; ++k) attn[k] *= rs;
    }
    s_attn[h][l15] = attn[l15];
    if (l15 < 8) s_attn[h][16 + l15] = attn[16 + l15];

    // ---- wkin[h][c] = sum_k attn[k] * kin[k][c] (4-acc) ----
    for (int t = 0; t < 7; ++t) {
        int c = t * 16 + l15;
        if (c < 99) {
            float a0 = 0.0f, a1 = 0.0f, a2 = 0.0f, a3 = 0.0f;
            #pragma unroll
            for (int k = 0; k < KNN; k += 4) {
                a0 += attn[k + 0] * s_kin[k + 0][c];
                a1 += attn[k + 1] * s_kin[k + 1][c];
                a2 += attn[k + 2] * s_kin[k + 2][c];
                a3 += attn[k + 3] * s_kin[k + 3][c];
            }
            s_wkin[h][c] = (a0 + a1) + (a2 + a3);
        }
    }
    // ---- v1[k][u] = kin[k] . Wv1[:,u] (4-acc) ----
    for (int t = 0; t < 6; ++t) {
        int k = (t * 64 + lane) >> 4;
        const float4* k4 = (const float4*)s_kin[k];
        const float* wv = &Wv1[l15];
        float a0 = 0.0f, a1 = 0.0f, a2 = 0.0f, a3 = 0.0f;
        #pragma unroll
        for (int c4 = 0; c4 < 24; c4 += 4) {
            float4 x0 = k4[c4 + 0];
            a0 += x0.x * wv[((c4 + 0) * 4 + 0) * 16] + x0.y * wv[((c4 + 0) * 4 + 1) * 16]
                + x0.z * wv[((c4 + 0) * 4 + 2) * 16] + x0.w * wv[((c4 + 0) * 4 + 3) * 16];
            float4 x1 = k4[c4 + 1];
            a1 += x1.x * wv[((c4 + 1) * 4 + 0) * 16] + x1.y * wv[((c4 + 1) * 4 + 1) * 16]
                + x1.z * wv[((c4 + 1) * 4 + 2) * 16] + x1.w * wv[((c4 + 1) * 4 + 3) * 16];
            float4 x2 = k4[c4 + 2];
            a2 += x2.x * wv[((c4 + 2) * 4 + 0) * 16] + x2.y * wv[((c4 + 2) * 4 + 1) * 16]
                + x2.z * wv[((c4 + 2) * 4 + 2) * 16] + x2.w * wv[((c4 + 2) * 4 + 3) * 16];
            float4 x3 = k4[c4 + 3];
            a3 += x3.x * wv[((c4 + 3) * 4 + 0) * 16] + x3.y * wv[((c4 + 3) * 4 + 1) * 16]
                + x3.z * wv[((c4 + 3) * 4 + 2) * 16] + x3.w * wv[((c4 + 3) * 4 + 3) * 16];
        }
        float acc = (a0 + a1) + (a2 + a3);
        acc += s_kin[k][96] * wv[96 * 16] + s_kin[k][97] * wv[97 * 16]
             + s_kin[k][98] * wv[98 * 16];
        s_v1[k][l15] = acc;
    }
    WB();

    // ---- o0[lane] = sum_c wkin[h][c] * Wv0[c, lane] (4-acc) ----
    {
        float a0 = 0.0f, a1 = 0.0f, a2 = 0.0f, a3 = 0.0f;
        for (int c = 0; c < 96; c += 4) {
            a0 += s_wkin[h][c + 0] * Wv0[(c + 0) * 64 + lane];
            a1 += s_wkin[h][c + 1] * Wv0[(c + 1) * 64 + lane];
            a2 += s_wkin[h][c + 2] * Wv0[(c + 2) * 64 + lane];
            a3 += s_wkin[h][c + 3] * Wv0[(c + 3) * 64 + lane];
        }
        a0 += s_wkin[h][96] * Wv0[96 * 64 + lane];
        a1 += s_wkin[h][97] * Wv0[97 * 64 + lane];
        a2 += s_wkin[h][98] * Wv0[98 * 64 + lane];
        s_o0[lane] = (a0 + a1) + (a2 + a3);
    }
    WB();

    // ---- out0 = o0 @ Wo0 + node0 @ Wself + b0 (4-acc) ----
    {
        float a0 = b0[lane], a1 = 0.0f, a2 = 0.0f, a3 = 0.0f;
        for (int t = 0; t < 64; t += 4) {
            a0 += s_o0[t + 0] * Wo0[(t + 0) * 64 + lane];
            a1 += s_o0[t + 1] * Wo0[(t + 1) * 64 + lane];
            a2 += s_o0[t + 2] * Wo0[(t + 2) * 64 + lane];
            a3 += s_o0[t + 3] * Wo0[(t + 3) * 64 + lane];
        }
        for (int t = 0; t < 64; t += 4) {
            a0 += s_qin[t + 0] * Wself[(t + 0) * 64 + lane];
            a1 += s_qin[t + 1] * Wself[(t + 1) * 64 + lane];
            a2 += s_qin[t + 2] * Wself[(t + 2) * 64 + lane];
            a3 += s_qin[t + 3] * Wself[(t + 3) * 64 + lane];
        }
        out_state[i * D0_ + lane] = (a0 + a1) + (a2 + a3);
    }
    // ---- coef[k][c] = sum_h attn[h][k] * v1[k][h*4+c] ----
    for (int f = lane; f < KNN * 4; f += 64) {
        int k = f >> 2, c = f & 3;
        float a2 = 0.0f;
        #pragma unroll
        for (int hh = 0; hh < 4; ++hh) a2 += s_attn[hh][k] * s_v1[k][hh * 4 + c];
        s_coef[k][c] = a2;
    }
    WB();

    // ---- vector message -> xyz shift ----
    if (lane < 3) {
        float o1 = 0.0f;
        #pragma unroll
        for (int k = 0; k < KNN; ++k) {
            float t = s_coef[k][0] * s_dir[k][lane];
            t += s_coef[k][1] * s_l1j[k][0][lane];
            t += s_coef[k][2] * s_l1j[k][1][lane];
            t += s_coef[k][3] * s_l1j[k][2][lane];
            o1 += t;
        }
        out_xyz[i * 3 + lane] = s_xi[lane] + o1 / 100.0f;
    }
}

extern "C" void kernel_launch(void* const* d_in, const int* in_sizes, int n_in,
                              void* d_out, int out_size, void* d_ws, size_t ws_size,
                              hipStream_t stream) {
    const int*   seq    = (const int*)d_in[0];
    const float* xyz    = (const float*)d_in[1];
    const int*   aamask = (const int*)d_in[2];
    const int*   nbonds = (const int*)d_in[3];
    const float* state  = (const float*)d_in[4];
    const float* grads  = (const float*)d_in[5];
    const float* We    = (const float*)d_in[7];
    const float* be    = (const float*)d_in[8];
    const float* Wq    = (const float*)d_in[9];
    const float* Wk    = (const float*)d_in[10];
    const float* Wv0   = (const float*)d_in[11];
    const float* Wv1   = (const float*)d_in[12];
    const float* Wo0   = (const float*)d_in[13];
    const float* Wself = (const float*)d_in[14];
    const float* b0    = (const float*)d_in[15];

    float* out_xyz   = (float*)d_out;
    float* out_state = out_xyz + MTOT * 3;

    char* ws = (char*)d_ws;
    int*    cnt  = (int*)ws;                              // 16 B
    float4* pact = (float4*)(ws + 16);                    // (MTOT+256)*16 = 151552 B
    int*    idx  = (int*)(ws + 16 + 151552);              // 884736 B

    hipMemsetAsync(cnt, 0, 16, stream);
    k_prep<<<(MTOT * D0_ / 4 + 255) / 256, 256, 0, stream>>>(
        seq, xyz, aamask, (const float4*)state, (float4*)out_state,
        pact, out_xyz, cnt);
    k_nbr<<<(MTOT + WPB - 1) / WPB, WPB * 64, 0, stream>>>(pact, cnt, idx);
    k_attn<<<MTOT, 64, 0, stream>>>(xyz, seq, nbonds, state, grads, We, be, Wq, Wk,
                                    Wv0, Wv1, Wo0, Wself, b0, pact, cnt, idx,
                                    out_xyz, out_state);
}